// Round 5
// baseline (886.610 us; speedup 1.0000x reference)
//
#include <hip/hip_runtime.h>
#include <hip/hip_bf16.h>

// SoftmaxAttention on MI355X (gfx950), bf16 MFMA pipeline:
//   1. cast x (1 launch) + Wq/Wk/Wv/Wo (1 fused launch)  fp32 -> bf16
//   2. gemm_qkv: z=0 Q = x@Wq^T -> [B,H,T,Dh]; z=1 K likewise;
//      z=2 Vt = Wv@x^T -> [B,H,Dh,T] (operand-swapped so the epilogue is coalesced)
//   3. attn_fwd: flash-style causal attention, O -> [B,T,D] bf16 (reuses x_bf16 slot)
//   4. gemm_out: out = O @ Wo^T -> fp32 d_out
//
// Storage:
//   d_out (64 MiB fp32) doubles as scratch for Q (first 32 MiB) and K (second
//   32 MiB) — both are fully consumed by attn_fwd before gemm_out overwrites
//   d_out with the final fp32 result. Harness validates d_out only after the
//   launch completes, so this is safe and halves the workspace requirement.
//   Workspace (96 MiB):
//     [0,  32M) x_bf16, later reused as O (attn output)
//     [32M,40M) Wq_b  [40M,48M) Wk_b  [48M,56M) Wv_b  [56M,64M) Wo_b
//     [64M,96M) Vt

typedef __attribute__((ext_vector_type(4))) float f32x4;
typedef __attribute__((ext_vector_type(8))) short s16x8;
using bf16 = __hip_bfloat16;

#define MFMA_BF16 __builtin_amdgcn_mfma_f32_16x16x32_bf16

__device__ __forceinline__ void gload16(const bf16* g, bf16* l) {
  __builtin_amdgcn_global_load_lds(
      (const __attribute__((address_space(1))) void*)g,
      (__attribute__((address_space(3))) void*)l, 16, 0, 0);
}

// XCD-aware bijective swizzle (T1, m192/m204): valid since nwg%8==0.
// Physical bid%8 == XCD (round-robin dispatch); give each XCD a contiguous
// chunk of logical tile space so neighboring tiles share its private L2.
__device__ __forceinline__ int xcd_swz(int bid, int nwg) {
  return (bid & 7) * (nwg >> 3) + (bid >> 3);
}

// ---------------------------------------------------------------- casts
__global__ __launch_bounds__(256) void cast_f32_to_bf16(
    const float* __restrict__ in, bf16* __restrict__ out, int n8) {
  int i = blockIdx.x * 256 + threadIdx.x;
  if (i >= n8) return;
  const float4* p = reinterpret_cast<const float4*>(in) + (size_t)i * 2;
  float4 a = p[0], b = p[1];
  union { s16x8 v; bf16 h[8]; } u;
  u.h[0] = __float2bfloat16(a.x); u.h[1] = __float2bfloat16(a.y);
  u.h[2] = __float2bfloat16(a.z); u.h[3] = __float2bfloat16(a.w);
  u.h[4] = __float2bfloat16(b.x); u.h[5] = __float2bfloat16(b.y);
  u.h[6] = __float2bfloat16(b.z); u.h[7] = __float2bfloat16(b.w);
  reinterpret_cast<s16x8*>(out)[i] = u.v;
}

__global__ __launch_bounds__(256) void cast4_f32_to_bf16(
    const float* __restrict__ i0, const float* __restrict__ i1,
    const float* __restrict__ i2, const float* __restrict__ i3,
    bf16* __restrict__ o0, bf16* __restrict__ o1,
    bf16* __restrict__ o2, bf16* __restrict__ o3, int n8) {
  const int z = blockIdx.y;
  const float* in = (z == 0) ? i0 : (z == 1) ? i1 : (z == 2) ? i2 : i3;
  bf16* out = (z == 0) ? o0 : (z == 1) ? o1 : (z == 2) ? o2 : o3;
  int i = blockIdx.x * 256 + threadIdx.x;
  if (i >= n8) return;
  const float4* p = reinterpret_cast<const float4*>(in) + (size_t)i * 2;
  float4 a = p[0], b = p[1];
  union { s16x8 v; bf16 h[8]; } u;
  u.h[0] = __float2bfloat16(a.x); u.h[1] = __float2bfloat16(a.y);
  u.h[2] = __float2bfloat16(a.z); u.h[3] = __float2bfloat16(a.w);
  u.h[4] = __float2bfloat16(b.x); u.h[5] = __float2bfloat16(b.y);
  u.h[6] = __float2bfloat16(b.z); u.h[7] = __float2bfloat16(b.w);
  reinterpret_cast<s16x8*>(out)[i] = u.v;
}

// ------------------------------------------------- shared GEMM mainloop
// C[128x128] tile = A[m0:m0+128, :2048] * B[n0:n0+128, :2048]^T
// A,B row-major [rows][2048] bf16. 256 threads = 4 waves (2x2), each wave 64x64.
// m97 structure: BK=64, global_load_lds width-16 staging, 2 barriers/K-step.
// (T2 LDS swizzle deliberately NOT applied: null at the 2-barrier structure.)
__device__ __forceinline__ void gemm_tile_mainloop(
    const bf16* __restrict__ A, const bf16* __restrict__ Bm,
    bf16* sA, bf16* sB, int m0, int n0, f32x4 (&acc)[4][4]) {
  const int tid = threadIdx.x;
  const int lane = tid & 63;
  const int w = tid >> 6;
  const int wm = w >> 1, wn = w & 1;
  const int lm = lane & 15, lg = lane >> 4;

  for (int kt = 0; kt < 2048; kt += 64) {
#pragma unroll
    for (int i = 0; i < 4; ++i) {
      int e = (i * 256 + tid) * 8;   // linear bf16 element in 128x64 tile
      int r = e >> 6;
      int c = e & 63;
      gload16(A + (size_t)(m0 + r) * 2048 + kt + c, sA + e);
      gload16(Bm + (size_t)(n0 + r) * 2048 + kt + c, sB + e);
    }
    __syncthreads();
#pragma unroll
    for (int ks = 0; ks < 64; ks += 32) {
      s16x8 af[4], bfr[4];
#pragma unroll
      for (int f = 0; f < 4; ++f)
        af[f] = *(const s16x8*)(sA + (wm * 64 + f * 16 + lm) * 64 + ks + lg * 8);
#pragma unroll
      for (int f = 0; f < 4; ++f)
        bfr[f] = *(const s16x8*)(sB + (wn * 64 + f * 16 + lm) * 64 + ks + lg * 8);
#pragma unroll
      for (int fm = 0; fm < 4; ++fm)
#pragma unroll
        for (int fn = 0; fn < 4; ++fn)
          acc[fm][fn] = MFMA_BF16(af[fm], bfr[fn], acc[fm][fn], 0, 0, 0);
    }
    __syncthreads();
  }
}

// ------------------------------------------------------------ QKV GEMM
// z=0: Q -> [B,H,T,Dh]; z=1: K -> [B,H,T,Dh]
// z=2: Vt = Wv @ x^T -> [B,H,Dh,T]  (A=Wv so output rows are d; coalesced)
__global__ __launch_bounds__(256, 2) void gemm_qkv(
    const bf16* __restrict__ X,
    const bf16* __restrict__ Wqb, const bf16* __restrict__ Wkb,
    const bf16* __restrict__ Wvb,
    bf16* __restrict__ Qb, bf16* __restrict__ Kb, bf16* __restrict__ Vtb) {
  __shared__ alignas(16) bf16 sA[128 * 64];
  __shared__ alignas(16) bf16 sB[128 * 64];
  const int z = blockIdx.z;
  // T1 swizzle over the 16x64 (x,y) tile plane (1024 blocks, %8==0)
  const int swz = xcd_swz(blockIdx.y * 16 + blockIdx.x, 1024);

  const int tid = threadIdx.x, lane = tid & 63, w = tid >> 6;
  const int wm = w >> 1, wn = w & 1;
  const int lm = lane & 15, lg = lane >> 4;

  if (z < 2) {
    const bf16* Wb = (z == 0) ? Wqb : Wkb;
    bf16* out = (z == 0) ? Qb : Kb;
    const int m0 = (swz >> 4) * 128, n0 = (swz & 15) * 128;   // m: (b,t)  n: (h,d)
    f32x4 acc[4][4] = {};
    gemm_tile_mainloop(X, Wb, sA, sB, m0, n0, acc);
#pragma unroll
    for (int fm = 0; fm < 4; ++fm)
#pragma unroll
      for (int fn = 0; fn < 4; ++fn)
#pragma unroll
        for (int j = 0; j < 4; ++j) {
          int gr = m0 + wm * 64 + fm * 16 + lg * 4 + j;   // (b, t)
          int gc = n0 + wn * 64 + fn * 16 + lm;           // (h, d)
          int b = gr >> 11, t = gr & 2047;
          int h = gc >> 7, d = gc & 127;
          out[((((size_t)b * 16 + h) * 2048 + t) << 7) + d] =
              __float2bfloat16(acc[fm][fn][j]);
        }
  } else {
    // Vt: A = Wv (2048 rows), B = x (8192 rows); m over d-rows, n over t-cols
    const int m0 = (swz & 15) * 128, n0 = (swz >> 4) * 128;
    f32x4 acc[4][4] = {};
    gemm_tile_mainloop(Wvb, X, sA, sB, m0, n0, acc);
#pragma unroll
    for (int fm = 0; fm < 4; ++fm)
#pragma unroll
      for (int fn = 0; fn < 4; ++fn)
#pragma unroll
        for (int j = 0; j < 4; ++j) {
          int gr = m0 + wm * 64 + fm * 16 + lg * 4 + j;   // (h, d)
          int gc = n0 + wn * 64 + fn * 16 + lm;           // (b, t)
          int h = gr >> 7, d = gr & 127;
          int b = gc >> 11, t = gc & 2047;
          Vtb[((((size_t)b * 16 + h) * 128 + d) << 11) + t] =
              __float2bfloat16(acc[fm][fn][j]);
        }
  }
}

// ------------------------------------------------------------ out GEMM
__global__ __launch_bounds__(256, 2) void gemm_out(
    const bf16* __restrict__ Ob, const bf16* __restrict__ Wob,
    float* __restrict__ out) {
  __shared__ alignas(16) bf16 sA[128 * 64];
  __shared__ alignas(16) bf16 sB[128 * 64];
  const int swz = xcd_swz(blockIdx.y * 16 + blockIdx.x, 1024);
  const int m0 = (swz >> 4) * 128, n0 = (swz & 15) * 128;
  f32x4 acc[4][4] = {};
  gemm_tile_mainloop(Ob, Wob, sA, sB, m0, n0, acc);

  const int tid = threadIdx.x, lane = tid & 63, w = tid >> 6;
  const int wm = w >> 1, wn = w & 1;
  const int lm = lane & 15, lg = lane >> 4;
#pragma unroll
  for (int fm = 0; fm < 4; ++fm)
#pragma unroll
    for (int fn = 0; fn < 4; ++fn)
#pragma unroll
      for (int j = 0; j < 4; ++j) {
        int gr = m0 + wm * 64 + fm * 16 + lg * 4 + j;
        int gc = n0 + wn * 64 + fn * 16 + lm;
        out[(size_t)gr * 2048 + gc] = acc[fm][fn][j];
      }
}

// ---------------------------------------------------------- attention
// grid 1024 = (16 q-blocks x 64 bh), swizzled so each XCD keeps 8 bh's K/V
// (8 x 512KB = 4MB = one XCD L2). 4 waves/block, wave owns 32 q-rows; no
// block barrier in the main loop, so per-wave causal early-exit is safe.
// Q,K: [B,H,T,128]; Vt: [B,H,128,T]; O: [B,T,2048] bf16.
__global__ __launch_bounds__(256, 2) void attn_fwd(
    const bf16* __restrict__ Q, const bf16* __restrict__ K,
    const bf16* __restrict__ Vt, bf16* __restrict__ O) {
  __shared__ alignas(16) bf16 sP[4][32][72];   // per-wave P scratch, pad 72
  const int swz = xcd_swz(blockIdx.y * 16 + blockIdx.x, 1024);
  const int bh = swz >> 4;                      // 64 bh groups
  const int b = bh >> 4, h = bh & 15;
  const bf16* Qp = Q + (size_t)bh * 2048 * 128;
  const bf16* Kp = K + (size_t)bh * 2048 * 128;
  const bf16* Vp = Vt + (size_t)bh * 128 * 2048;
  const int tid = threadIdx.x, lane = tid & 63, w = tid >> 6;
  const int q0 = (swz & 15) * 128;
  const int qw = q0 + w * 32;          // wave's first q row
  const int lm = lane & 15, lg = lane >> 4;

  // Q fragments held in registers for the whole block
  s16x8 aq[2][4];
#pragma unroll
  for (int fm = 0; fm < 2; ++fm)
#pragma unroll
    for (int kd = 0; kd < 4; ++kd)
      aq[fm][kd] = *(const s16x8*)(Qp + (size_t)(qw + fm * 16 + lm) * 128 + kd * 32 + lg * 8);

  float mrun[2][4], lrun[2][4];
  f32x4 o[2][8] = {};
#pragma unroll
  for (int fm = 0; fm < 2; ++fm)
#pragma unroll
    for (int j = 0; j < 4; ++j) { mrun[fm][j] = -1e30f; lrun[fm][j] = 0.f; }

  const float scale = 0.08838834764831845f;   // 1/sqrt(128)
  const int ntiles = (q0 >> 6) + 2;           // causal: tiles up to block diagonal
  for (int t = 0; t < ntiles; ++t) {
    const int kv0 = t * 64;
    if (kv0 > qw + 31) continue;              // wave-uniform: tile fully masked
    // ---- S = Q K^T  (per wave: 32 x 64)
    f32x4 s[2][4] = {};
    __builtin_amdgcn_s_setprio(1);            // T5: independent waves, m191 regime
#pragma unroll
    for (int kd = 0; kd < 4; ++kd)
#pragma unroll
      for (int fn = 0; fn < 4; ++fn) {
        s16x8 bk = *(const s16x8*)(Kp + (size_t)(kv0 + fn * 16 + lm) * 128 + kd * 32 + lg * 8);
#pragma unroll
        for (int fm = 0; fm < 2; ++fm)
          s[fm][fn] = MFMA_BF16(aq[fm][kd], bk, s[fm][fn], 0, 0, 0);
      }
    __builtin_amdgcn_s_setprio(0);
    // ---- scale + causal mask
    const bool needmask = (kv0 + 63) > qw;
#pragma unroll
    for (int fm = 0; fm < 2; ++fm)
#pragma unroll
      for (int fn = 0; fn < 4; ++fn)
#pragma unroll
        for (int j = 0; j < 4; ++j) {
          float sv = s[fm][fn][j] * scale;
          if (needmask) {
            int qr = qw + fm * 16 + lg * 4 + j;
            int kc = kv0 + fn * 16 + lm;
            if (kc > qr) sv = -1e30f;
          }
          s[fm][fn][j] = sv;
        }
    // ---- online softmax: row max (16-lane group reduce), rescale, exp, row sum
#pragma unroll
    for (int fm = 0; fm < 2; ++fm)
#pragma unroll
      for (int j = 0; j < 4; ++j) {
        float pm = fmaxf(fmaxf(s[fm][0][j], s[fm][1][j]),
                         fmaxf(s[fm][2][j], s[fm][3][j]));
        pm = fmaxf(pm, __shfl_xor(pm, 1));
        pm = fmaxf(pm, __shfl_xor(pm, 2));
        pm = fmaxf(pm, __shfl_xor(pm, 4));
        pm = fmaxf(pm, __shfl_xor(pm, 8));
        float mnew = fmaxf(mrun[fm][j], pm);
        float sf = __expf(mrun[fm][j] - mnew);
        mrun[fm][j] = mnew;
        lrun[fm][j] *= sf;
#pragma unroll
        for (int fn = 0; fn < 8; ++fn) o[fm][fn][j] *= sf;
      }
#pragma unroll
    for (int fm = 0; fm < 2; ++fm) {
#pragma unroll
      for (int fn = 0; fn < 4; ++fn)
#pragma unroll
        for (int j = 0; j < 4; ++j)
          s[fm][fn][j] = __expf(s[fm][fn][j] - mrun[fm][j]);
#pragma unroll
      for (int j = 0; j < 4; ++j) {
        float rs = s[fm][0][j] + s[fm][1][j] + s[fm][2][j] + s[fm][3][j];
        rs += __shfl_xor(rs, 1);
        rs += __shfl_xor(rs, 2);
        rs += __shfl_xor(rs, 4);
        rs += __shfl_xor(rs, 8);
        lrun[fm][j] += rs;
      }
    }
    // ---- P -> LDS (transpose to MFMA A-layout), bf16
#pragma unroll
    for (int fm = 0; fm < 2; ++fm)
#pragma unroll
      for (int fn = 0; fn < 4; ++fn)
#pragma unroll
        for (int j = 0; j < 4; ++j)
          sP[w][fm * 16 + lg * 4 + j][fn * 16 + lm] = __float2bfloat16(s[fm][fn][j]);
    // per-wave LDS ops execute in order in HW; this pins the compiler's order
    asm volatile("" ::: "memory");
    // ---- O += P V   (Vt rows are d, contiguous in kv)
    __builtin_amdgcn_s_setprio(1);
#pragma unroll
    for (int kc = 0; kc < 2; ++kc) {
      s16x8 ap[2];
#pragma unroll
      for (int fm = 0; fm < 2; ++fm)
        ap[fm] = *(const s16x8*)(&sP[w][fm * 16 + lm][kc * 32 + lg * 8]);
#pragma unroll
      for (int fn = 0; fn < 8; ++fn) {
        s16x8 bv = *(const s16x8*)(Vp + (size_t)(fn * 16 + lm) * 2048 + kv0 + kc * 32 + lg * 8);
#pragma unroll
        for (int fm = 0; fm < 2; ++fm)
          o[fm][fn] = MFMA_BF16(ap[fm], bv, o[fm][fn], 0, 0, 0);
      }
    }
    __builtin_amdgcn_s_setprio(0);
  }
  // ---- normalize and write O as [B,T,2048]
#pragma unroll
  for (int fm = 0; fm < 2; ++fm)
#pragma unroll
    for (int j = 0; j < 4; ++j) {
      float inv = 1.0f / lrun[fm][j];
#pragma unroll
      for (int fn = 0; fn < 8; ++fn) {
        int q = qw + fm * 16 + lg * 4 + j;
        int d = fn * 16 + lm;
        O[(size_t)(b * 2048 + q) * 2048 + h * 128 + d] =
            __float2bfloat16(o[fm][fn][j] * inv);
      }
    }
}

// ---------------------------------------------------------------- launch
extern "C" void kernel_launch(void* const* d_in, const int* in_sizes, int n_in,
                              void* d_out, int out_size, void* d_ws, size_t ws_size,
                              hipStream_t stream) {
  const float* x  = (const float*)d_in[0];
  const float* Wq = (const float*)d_in[1];
  const float* Wk = (const float*)d_in[2];
  const float* Wv = (const float*)d_in[3];
  const float* Wo = (const float*)d_in[4];
  float* out = (float*)d_out;

  if (ws_size < 100663296u) return;   // need 96 MiB scratch

  char* ws = (char*)d_ws;
  bf16* xb  = (bf16*)(ws);                 // 32 MiB, reused as attn output O
  bf16* wqb = (bf16*)(ws + 33554432u);
  bf16* wkb = (bf16*)(ws + 41943040u);
  bf16* wvb = (bf16*)(ws + 50331648u);
  bf16* wob = (bf16*)(ws + 58720256u);
  bf16* Vtb = (bf16*)(ws + 67108864u);
  // Q and K live in d_out (64 MiB): dead storage until gemm_out runs last.
  bf16* Qb  = (bf16*)d_out;
  bf16* Kb  = (bf16*)d_out + 16777216u;

  // 1. casts
  cast_f32_to_bf16<<<8192, 256, 0, stream>>>(x, xb, 2097152);
  cast4_f32_to_bf16<<<dim3(2048, 4), 256, 0, stream>>>(
      Wq, Wk, Wv, Wo, wqb, wkb, wvb, wob, 524288);

  // 2. Q/K/V projections (z selects weight, operand order, epilogue layout)
  gemm_qkv<<<dim3(16, 64, 3), 256, 0, stream>>>(xb, wqb, wkb, wvb, Qb, Kb, Vtb);

  // 3. causal flash attention -> O (reuses xb slot; Q/K consumed here)
  attn_fwd<<<dim3(16, 64), 256, 0, stream>>>(Qb, Kb, Vtb, xb);

  // 4. output projection -> fp32 (overwrites Q/K scratch in d_out)
  gemm_out<<<dim3(16, 64), 256, 0, stream>>>(xb, wob, out);
}

// Round 9
// 708.253 us; speedup vs baseline: 1.2518x; 1.2518x over previous
//
#include <hip/hip_runtime.h>
#include <hip/hip_bf16.h>

// SoftmaxAttention on MI355X (gfx950), bf16 MFMA pipeline:
//   1. cast x (1 launch) + Wq/Wk/Wv/Wo (1 fused launch)  fp32 -> bf16
//   2. gemm_qkv: z=0 Q = x@Wq^T -> [B,H,T,Dh]; z=1 K likewise;
//      z=2 Vt = Wv@x^T -> [B,H,Dh,T] (operand-swapped so the epilogue is coalesced)
//   3. attn_fwd: flash-style causal attention, O -> [B,T,D] bf16 (reuses x_bf16 slot)
//      R5: causal pair-balancing (wave does tasks p and 63-p: exactly 33 tiles
//      each) + V-register prefetch under softmax. Was: CU-level imbalance ->
//      14% occupancy, 6.4% MfmaUtil, 443 us.
//   4. gemm_out: out = O @ Wo^T -> fp32 d_out
//
// Storage:
//   d_out (64 MiB fp32) doubles as scratch for Q (first 32 MiB) and K (second
//   32 MiB) — both are fully consumed by attn_fwd before gemm_out overwrites
//   d_out with the final fp32 result.
//   Workspace (96 MiB):
//     [0,  32M) x_bf16, later reused as O (attn output)
//     [32M,40M) Wq_b  [40M,48M) Wk_b  [48M,56M) Wv_b  [56M,64M) Wo_b
//     [64M,96M) Vt

typedef __attribute__((ext_vector_type(4))) float f32x4;
typedef __attribute__((ext_vector_type(8))) short s16x8;
using bf16 = __hip_bfloat16;

#define MFMA_BF16 __builtin_amdgcn_mfma_f32_16x16x32_bf16

__device__ __forceinline__ void gload16(const bf16* g, bf16* l) {
  __builtin_amdgcn_global_load_lds(
      (const __attribute__((address_space(1))) void*)g,
      (__attribute__((address_space(3))) void*)l, 16, 0, 0);
}

// XCD-aware bijective swizzle (T1, m192/m204): valid since nwg%8==0.
__device__ __forceinline__ int xcd_swz(int bid, int nwg) {
  return (bid & 7) * (nwg >> 3) + (bid >> 3);
}

// ---------------------------------------------------------------- casts
__global__ __launch_bounds__(256) void cast_f32_to_bf16(
    const float* __restrict__ in, bf16* __restrict__ out, int n8) {
  int i = blockIdx.x * 256 + threadIdx.x;
  if (i >= n8) return;
  const float4* p = reinterpret_cast<const float4*>(in) + (size_t)i * 2;
  float4 a = p[0], b = p[1];
  union { s16x8 v; bf16 h[8]; } u;
  u.h[0] = __float2bfloat16(a.x); u.h[1] = __float2bfloat16(a.y);
  u.h[2] = __float2bfloat16(a.z); u.h[3] = __float2bfloat16(a.w);
  u.h[4] = __float2bfloat16(b.x); u.h[5] = __float2bfloat16(b.y);
  u.h[6] = __float2bfloat16(b.z); u.h[7] = __float2bfloat16(b.w);
  reinterpret_cast<s16x8*>(out)[i] = u.v;
}

__global__ __launch_bounds__(256) void cast4_f32_to_bf16(
    const float* __restrict__ i0, const float* __restrict__ i1,
    const float* __restrict__ i2, const float* __restrict__ i3,
    bf16* __restrict__ o0, bf16* __restrict__ o1,
    bf16* __restrict__ o2, bf16* __restrict__ o3, int n8) {
  const int z = blockIdx.y;
  const float* in = (z == 0) ? i0 : (z == 1) ? i1 : (z == 2) ? i2 : i3;
  bf16* out = (z == 0) ? o0 : (z == 1) ? o1 : (z == 2) ? o2 : o3;
  int i = blockIdx.x * 256 + threadIdx.x;
  if (i >= n8) return;
  const float4* p = reinterpret_cast<const float4*>(in) + (size_t)i * 2;
  float4 a = p[0], b = p[1];
  union { s16x8 v; bf16 h[8]; } u;
  u.h[0] = __float2bfloat16(a.x); u.h[1] = __float2bfloat16(a.y);
  u.h[2] = __float2bfloat16(a.z); u.h[3] = __float2bfloat16(a.w);
  u.h[4] = __float2bfloat16(b.x); u.h[5] = __float2bfloat16(b.y);
  u.h[6] = __float2bfloat16(b.z); u.h[7] = __float2bfloat16(b.w);
  reinterpret_cast<s16x8*>(out)[i] = u.v;
}

// ------------------------------------------------- shared GEMM mainloop
// m97 structure: BK=64, global_load_lds width-16 staging, 2 barriers/K-step.
__device__ __forceinline__ void gemm_tile_mainloop(
    const bf16* __restrict__ A, const bf16* __restrict__ Bm,
    bf16* sA, bf16* sB, int m0, int n0, f32x4 (&acc)[4][4]) {
  const int tid = threadIdx.x;
  const int lane = tid & 63;
  const int w = tid >> 6;
  const int wm = w >> 1, wn = w & 1;
  const int lm = lane & 15, lg = lane >> 4;

  for (int kt = 0; kt < 2048; kt += 64) {
#pragma unroll
    for (int i = 0; i < 4; ++i) {
      int e = (i * 256 + tid) * 8;   // linear bf16 element in 128x64 tile
      int r = e >> 6;
      int c = e & 63;
      gload16(A + (size_t)(m0 + r) * 2048 + kt + c, sA + e);
      gload16(Bm + (size_t)(n0 + r) * 2048 + kt + c, sB + e);
    }
    __syncthreads();
#pragma unroll
    for (int ks = 0; ks < 64; ks += 32) {
      s16x8 af[4], bfr[4];
#pragma unroll
      for (int f = 0; f < 4; ++f)
        af[f] = *(const s16x8*)(sA + (wm * 64 + f * 16 + lm) * 64 + ks + lg * 8);
#pragma unroll
      for (int f = 0; f < 4; ++f)
        bfr[f] = *(const s16x8*)(sB + (wn * 64 + f * 16 + lm) * 64 + ks + lg * 8);
#pragma unroll
      for (int fm = 0; fm < 4; ++fm)
#pragma unroll
        for (int fn = 0; fn < 4; ++fn)
          acc[fm][fn] = MFMA_BF16(af[fm], bfr[fn], acc[fm][fn], 0, 0, 0);
    }
    __syncthreads();
  }
}

// ------------------------------------------------------------ QKV GEMM
__global__ __launch_bounds__(256, 2) void gemm_qkv(
    const bf16* __restrict__ X,
    const bf16* __restrict__ Wqb, const bf16* __restrict__ Wkb,
    const bf16* __restrict__ Wvb,
    bf16* __restrict__ Qb, bf16* __restrict__ Kb, bf16* __restrict__ Vtb) {
  __shared__ alignas(16) bf16 sA[128 * 64];
  __shared__ alignas(16) bf16 sB[128 * 64];
  const int z = blockIdx.z;
  const int swz = xcd_swz(blockIdx.y * 16 + blockIdx.x, 1024);

  const int tid = threadIdx.x, lane = tid & 63, w = tid >> 6;
  const int wm = w >> 1, wn = w & 1;
  const int lm = lane & 15, lg = lane >> 4;

  if (z < 2) {
    const bf16* Wb = (z == 0) ? Wqb : Wkb;
    bf16* out = (z == 0) ? Qb : Kb;
    const int m0 = (swz >> 4) * 128, n0 = (swz & 15) * 128;   // m: (b,t)  n: (h,d)
    f32x4 acc[4][4] = {};
    gemm_tile_mainloop(X, Wb, sA, sB, m0, n0, acc);
#pragma unroll
    for (int fm = 0; fm < 4; ++fm)
#pragma unroll
      for (int fn = 0; fn < 4; ++fn)
#pragma unroll
        for (int j = 0; j < 4; ++j) {
          int gr = m0 + wm * 64 + fm * 16 + lg * 4 + j;   // (b, t)
          int gc = n0 + wn * 64 + fn * 16 + lm;           // (h, d)
          int b = gr >> 11, t = gr & 2047;
          int h = gc >> 7, d = gc & 127;
          out[((((size_t)b * 16 + h) * 2048 + t) << 7) + d] =
              __float2bfloat16(acc[fm][fn][j]);
        }
  } else {
    // Vt: A = Wv (2048 rows), B = x (8192 rows); m over d-rows, n over t-cols
    const int m0 = (swz & 15) * 128, n0 = (swz >> 4) * 128;
    f32x4 acc[4][4] = {};
    gemm_tile_mainloop(Wvb, X, sA, sB, m0, n0, acc);
#pragma unroll
    for (int fm = 0; fm < 4; ++fm)
#pragma unroll
      for (int fn = 0; fn < 4; ++fn)
#pragma unroll
        for (int j = 0; j < 4; ++j) {
          int gr = m0 + wm * 64 + fm * 16 + lg * 4 + j;   // (h, d)
          int gc = n0 + wn * 64 + fn * 16 + lm;           // (b, t)
          int h = gr >> 7, d = gr & 127;
          int b = gc >> 11, t = gc & 2047;
          Vtb[((((size_t)b * 16 + h) * 128 + d) << 11) + t] =
              __float2bfloat16(acc[fm][fn][j]);
        }
  }
}

// ------------------------------------------------------------ out GEMM
__global__ __launch_bounds__(256, 2) void gemm_out(
    const bf16* __restrict__ Ob, const bf16* __restrict__ Wob,
    float* __restrict__ out) {
  __shared__ alignas(16) bf16 sA[128 * 64];
  __shared__ alignas(16) bf16 sB[128 * 64];
  const int swz = xcd_swz(blockIdx.y * 16 + blockIdx.x, 1024);
  const int m0 = (swz >> 4) * 128, n0 = (swz & 15) * 128;
  f32x4 acc[4][4] = {};
  gemm_tile_mainloop(Ob, Wob, sA, sB, m0, n0, acc);

  const int tid = threadIdx.x, lane = tid & 63, w = tid >> 6;
  const int wm = w >> 1, wn = w & 1;
  const int lm = lane & 15, lg = lane >> 4;
#pragma unroll
  for (int fm = 0; fm < 4; ++fm)
#pragma unroll
    for (int fn = 0; fn < 4; ++fn)
#pragma unroll
      for (int j = 0; j < 4; ++j) {
        int gr = m0 + wm * 64 + fm * 16 + lg * 4 + j;
        int gc = n0 + wn * 64 + fn * 16 + lm;
        out[(size_t)gr * 2048 + gc] = acc[fm][fn][j];
      }
}

// ---------------------------------------------------------- attention
// R5 pair-balanced: grid (8, 64) = 512 blocks, 4 waves each. Wave-task = 32
// q-rows; task t costs ~t/2+1 KV tiles. Wave (block.x, w) owns pair
// p = block.x*4+w and runs tasks {p, 63-p} sequentially: exactly 33 tiles per
// wave, so every SIMD in the device retires identical work (kills the causal
// tail that gave 14% occupancy). V fragments are prefetched into registers
// right after QK^T so their L2 latency hides under the softmax VALU chain.
// Q,K: [B,H,T,128]; Vt: [B,H,128,T]; O: [B,T,2048] bf16.
__global__ __launch_bounds__(256, 2) void attn_fwd(
    const bf16* __restrict__ Q, const bf16* __restrict__ K,
    const bf16* __restrict__ Vt, bf16* __restrict__ O) {
  __shared__ alignas(16) bf16 sP[4][32][72];   // per-wave P scratch, pad 72
  const int swz = xcd_swz(blockIdx.y * 8 + blockIdx.x, 512);
  const int bh = swz >> 3;                      // 64 bh groups
  const int b = bh >> 4, h = bh & 15;
  const bf16* Qp = Q + (size_t)bh * 2048 * 128;
  const bf16* Kp = K + (size_t)bh * 2048 * 128;
  const bf16* Vp = Vt + (size_t)bh * 128 * 2048;
  const int tid = threadIdx.x, lane = tid & 63, w = tid >> 6;
  const int pr = (swz & 7) * 4 + w;             // pair id 0..31
  const int lm = lane & 15, lg = lane >> 4;
  const float scale = 0.08838834764831845f;     // 1/sqrt(128)

  for (int task = 0; task < 2; ++task) {
    const int tt = (task == 0) ? pr : 63 - pr;  // tasks {p, 63-p}: 33 tiles total
    const int qw = tt * 32;                     // wave's first q row

    // Q fragments for this task
    s16x8 aq[2][4];
#pragma unroll
    for (int fm = 0; fm < 2; ++fm)
#pragma unroll
      for (int kd = 0; kd < 4; ++kd)
        aq[fm][kd] = *(const s16x8*)(Qp + (size_t)(qw + fm * 16 + lm) * 128 + kd * 32 + lg * 8);

    float mrun[2][4], lrun[2][4];
    f32x4 o[2][8] = {};
#pragma unroll
    for (int fm = 0; fm < 2; ++fm)
#pragma unroll
      for (int j = 0; j < 4; ++j) { mrun[fm][j] = -1e30f; lrun[fm][j] = 0.f; }

    const int ntiles = (qw >> 6) + 1;           // exact causal tile count
    for (int t = 0; t < ntiles; ++t) {
      const int kv0 = t * 64;
      // ---- S = Q K^T  (per wave: 32 x 64)
      f32x4 s[2][4] = {};
      __builtin_amdgcn_s_setprio(1);            // T5: independent waves
#pragma unroll
      for (int kd = 0; kd < 4; ++kd)
#pragma unroll
        for (int fn = 0; fn < 4; ++fn) {
          s16x8 bk = *(const s16x8*)(Kp + (size_t)(kv0 + fn * 16 + lm) * 128 + kd * 32 + lg * 8);
#pragma unroll
          for (int fm = 0; fm < 2; ++fm)
            s[fm][fn] = MFMA_BF16(aq[fm][kd], bk, s[fm][fn], 0, 0, 0);
        }
      __builtin_amdgcn_s_setprio(0);
      // ---- V prefetch: issue now, consume after softmax (latency hidden)
      s16x8 bv[2][8];
#pragma unroll
      for (int kc = 0; kc < 2; ++kc)
#pragma unroll
        for (int fn = 0; fn < 8; ++fn)
          bv[kc][fn] = *(const s16x8*)(Vp + (size_t)(fn * 16 + lm) * 2048 + kv0 + kc * 32 + lg * 8);
      // ---- scale + causal mask
      const bool needmask = (kv0 + 63) > qw;
#pragma unroll
      for (int fm = 0; fm < 2; ++fm)
#pragma unroll
        for (int fn = 0; fn < 4; ++fn)
#pragma unroll
          for (int j = 0; j < 4; ++j) {
            float sv = s[fm][fn][j] * scale;
            if (needmask) {
              int qr = qw + fm * 16 + lg * 4 + j;
              int kc = kv0 + fn * 16 + lm;
              if (kc > qr) sv = -1e30f;
            }
            s[fm][fn][j] = sv;
          }
      // ---- online softmax: row max (16-lane group reduce), rescale, exp, sum
#pragma unroll
      for (int fm = 0; fm < 2; ++fm)
#pragma unroll
        for (int j = 0; j < 4; ++j) {
          float pm = fmaxf(fmaxf(s[fm][0][j], s[fm][1][j]),
                           fmaxf(s[fm][2][j], s[fm][3][j]));
          pm = fmaxf(pm, __shfl_xor(pm, 1));
          pm = fmaxf(pm, __shfl_xor(pm, 2));
          pm = fmaxf(pm, __shfl_xor(pm, 4));
          pm = fmaxf(pm, __shfl_xor(pm, 8));
          float mnew = fmaxf(mrun[fm][j], pm);
          float sf = __expf(mrun[fm][j] - mnew);
          mrun[fm][j] = mnew;
          lrun[fm][j] *= sf;
#pragma unroll
          for (int fn = 0; fn < 8; ++fn) o[fm][fn][j] *= sf;
        }
#pragma unroll
      for (int fm = 0; fm < 2; ++fm) {
#pragma unroll
        for (int fn = 0; fn < 4; ++fn)
#pragma unroll
          for (int j = 0; j < 4; ++j)
            s[fm][fn][j] = __expf(s[fm][fn][j] - mrun[fm][j]);
#pragma unroll
        for (int j = 0; j < 4; ++j) {
          float rs = s[fm][0][j] + s[fm][1][j] + s[fm][2][j] + s[fm][3][j];
          rs += __shfl_xor(rs, 1);
          rs += __shfl_xor(rs, 2);
          rs += __shfl_xor(rs, 4);
          rs += __shfl_xor(rs, 8);
          lrun[fm][j] += rs;
        }
      }
      // ---- P -> LDS (transpose to MFMA A-layout), bf16
#pragma unroll
      for (int fm = 0; fm < 2; ++fm)
#pragma unroll
        for (int fn = 0; fn < 4; ++fn)
#pragma unroll
          for (int j = 0; j < 4; ++j)
            sP[w][fm * 16 + lg * 4 + j][fn * 16 + lm] = __float2bfloat16(s[fm][fn][j]);
      asm volatile("" ::: "memory");
      // ---- O += P V   (V already in registers)
      __builtin_amdgcn_s_setprio(1);
#pragma unroll
      for (int kc = 0; kc < 2; ++kc) {
        s16x8 ap[2];
#pragma unroll
        for (int fm = 0; fm < 2; ++fm)
          ap[fm] = *(const s16x8*)(&sP[w][fm * 16 + lm][kc * 32 + lg * 8]);
#pragma unroll
        for (int fn = 0; fn < 8; ++fn)
#pragma unroll
          for (int fm = 0; fm < 2; ++fm)
            o[fm][fn] = MFMA_BF16(ap[fm], bv[kc][fn], o[fm][fn], 0, 0, 0);
      }
      __builtin_amdgcn_s_setprio(0);
    }
    // ---- normalize and write O as [B,T,2048]
#pragma unroll
    for (int fm = 0; fm < 2; ++fm)
#pragma unroll
      for (int j = 0; j < 4; ++j) {
        float inv = 1.0f / lrun[fm][j];
#pragma unroll
        for (int fn = 0; fn < 8; ++fn) {
          int q = qw + fm * 16 + lg * 4 + j;
          int d = fn * 16 + lm;
          O[(size_t)(b * 2048 + q) * 2048 + h * 128 + d] =
              __float2bfloat16(o[fm][fn][j] * inv);
        }
      }
  }
}

// ---------------------------------------------------------------- launch
extern "C" void kernel_launch(void* const* d_in, const int* in_sizes, int n_in,
                              void* d_out, int out_size, void* d_ws, size_t ws_size,
                              hipStream_t stream) {
  const float* x  = (const float*)d_in[0];
  const float* Wq = (const float*)d_in[1];
  const float* Wk = (const float*)d_in[2];
  const float* Wv = (const float*)d_in[3];
  const float* Wo = (const float*)d_in[4];
  float* out = (float*)d_out;

  if (ws_size < 100663296u) return;   // need 96 MiB scratch

  char* ws = (char*)d_ws;
  bf16* xb  = (bf16*)(ws);                 // 32 MiB, reused as attn output O
  bf16* wqb = (bf16*)(ws + 33554432u);
  bf16* wkb = (bf16*)(ws + 41943040u);
  bf16* wvb = (bf16*)(ws + 50331648u);
  bf16* wob = (bf16*)(ws + 58720256u);
  bf16* Vtb = (bf16*)(ws + 67108864u);
  // Q and K live in d_out (64 MiB): dead storage until gemm_out runs last.
  bf16* Qb  = (bf16*)d_out;
  bf16* Kb  = (bf16*)d_out + 16777216u;

  // 1. casts
  cast_f32_to_bf16<<<8192, 256, 0, stream>>>(x, xb, 2097152);
  cast4_f32_to_bf16<<<dim3(2048, 4), 256, 0, stream>>>(
      Wq, Wk, Wv, Wo, wqb, wkb, wvb, wob, 524288);

  // 2. Q/K/V projections (z selects weight, operand order, epilogue layout)
  gemm_qkv<<<dim3(16, 64, 3), 256, 0, stream>>>(xb, wqb, wkb, wvb, Qb, Kb, Vtb);

  // 3. causal flash attention -> O (reuses xb slot; Q/K consumed here)
  attn_fwd<<<dim3(8, 64), 256, 0, stream>>>(Qb, Kb, Vtb, xb);

  // 4. output projection -> fp32 (overwrites Q/K scratch in d_out)
  gemm_out<<<dim3(16, 64), 256, 0, stream>>>(xb, wob, out);
}